// Round 4
// baseline (230.663 us; speedup 1.0000x reference)
//
#include <hip/hip_runtime.h>

#define NITER 10
#define PAD 8       // CSR segment padding / accumulator depth
#define NBLK 250    // main-kernel blocks (250*8 waves = 2000 nodes exactly)
#define MAIN_T 512  // 8 waves per block

// ---------------- helpers ----------------

__device__ __forceinline__ float bf2f_lo(uint32_t v) { return __uint_as_float(v << 16); }
__device__ __forceinline__ float bf2f_hi(uint32_t v) { return __uint_as_float(v & 0xFFFF0000u); }

__device__ __forceinline__ uint32_t f2bf_bits(float f) {  // RNE, top 16 bits
  uint32_t b = __float_as_uint(f);
  b += 0x7FFFu + ((b >> 16) & 1u);
  return b >> 16;
}
__device__ __forceinline__ uint32_t pack_bf16x2(float lo, float hi) {
  return f2bf_bits(lo) | (f2bf_bits(hi) << 16);
}

// ---------------- setup kernel 1: partial histograms + edge-array zeroing ----------------
// blocks 0..7: per-block LDS histogram over E/8 edges -> partS/partT[blk][n]
// blocks 8..31: zero the packed edge arrays (pad entries must be idx=0,w=+0)

__global__ __launch_bounds__(1024) void hist_zero_kernel(
    const int* __restrict__ src, const int* __restrict__ tgt,
    int* __restrict__ partS, int* __restrict__ partT,
    uint32_t* __restrict__ edges, int E, int N, int zwords) {
  if (blockIdx.x < 8) {
    __shared__ int h[4096];
    for (int i = threadIdx.x; i < 2 * N; i += 1024) h[i] = 0;
    __syncthreads();
    const int chunk = E / 8;
    const int base = blockIdx.x * chunk;
    for (int k = threadIdx.x; k < chunk; k += 1024) {
      int e = base + k;
      atomicAdd(&h[src[e]], 1);
      atomicAdd(&h[N + tgt[e]], 1);
    }
    __syncthreads();
    for (int i = threadIdx.x; i < N; i += 1024) {
      partS[blockIdx.x * 2048 + i] = h[i];
      partT[blockIdx.x * 2048 + i] = h[N + i];
    }
  } else {
    int tid = (blockIdx.x - 8) * 1024 + threadIdx.x;
    for (int i = tid; i < zwords; i += 24 * 1024) edges[i] = 0u;
  }
}

// ---------------- setup kernel 2: padded exclusive scan (+ zero barrier counters) ----------
// blockIdx.x 0 -> S, 1 -> T ; 256 threads x 8 = 2048 >= N+1

__global__ void scan_pad_kernel(const int* __restrict__ partS, const int* __restrict__ partT,
                                int* __restrict__ offS, int* __restrict__ offT,
                                int* __restrict__ curS, int* __restrict__ curT,
                                uint32_t* __restrict__ bar, int N) {
  if (blockIdx.x == 0 && threadIdx.x < 192) bar[threadIdx.x] = 0u;  // barrier ctrs + gen
  const int* part = (blockIdx.x == 0) ? partS : partT;
  int* off = (blockIdx.x == 0) ? offS : offT;
  int* cur = (blockIdx.x == 0) ? curS : curT;
  __shared__ int tsum[256];
  int tid = threadIdx.x;
  int base = tid * 8;
  int v[8];
  int s = 0;
#pragma unroll
  for (int i = 0; i < 8; ++i) {
    int idx = base + i;
    int c = 0;
    if (idx < N) {
#pragma unroll
      for (int k = 0; k < 8; ++k) c += part[k * 2048 + idx];
      c = (c + (PAD - 1)) & ~(PAD - 1);  // pad degree to multiple of PAD
    }
    v[i] = s;
    s += c;
  }
  tsum[tid] = s;
  __syncthreads();
  for (int d = 1; d < 256; d <<= 1) {
    int t = (tid >= d) ? tsum[tid - d] : 0;
    __syncthreads();
    tsum[tid] += t;
    __syncthreads();
  }
  int tbase = tsum[tid] - s;
#pragma unroll
  for (int i = 0; i < 8; ++i) {
    int idx = base + i;
    if (idx < N) {
      int o = tbase + v[i];
      off[idx] = o;
      cur[idx] = o;
    } else if (idx == N) {
      off[idx] = tbase + v[i];
    }
  }
}

// ---------------- setup kernel 3: scatter edges into CSR ----------------
// packed edge: low 16 = neighbor index, high 16 = bf16(w) bits

__global__ void scatter_kernel(const int* __restrict__ src, const int* __restrict__ tgt,
                               const float* __restrict__ w,
                               int* __restrict__ curS, int* __restrict__ curT,
                               uint32_t* __restrict__ edgeS, uint32_t* __restrict__ edgeT, int E) {
  int e = blockIdx.x * blockDim.x + threadIdx.x;
  if (e < E) {
    int s = src[e], t = tgt[e];
    uint32_t wb = __float_as_uint(w[e]);
    wb = (wb + 0x7FFFu + ((wb >> 16) & 1u)) & 0xFFFF0000u;
    int p = atomicAdd(&curS[s], 1);
    edgeS[p] = (uint32_t)t | wb;  // mu pass: grouped by src, gathers fx[tgt]
    int q = atomicAdd(&curT[t], 1);
    edgeT[q] = (uint32_t)s | wb;  // agg pass: grouped by tgt, gathers err[src]
  }
}

// ---------------- main cooperative kernel ----------------

// Tree barrier: 8 leaf counters (64B apart) -> root -> generation flag.
// Fully relaxed atomics: correctness comes from (a) vmcnt(0) drain of write-through
// sc1 stores before arrival, (b) all cross-block data read via agent-scope (LLC) loads.
__device__ __forceinline__ void gbar(uint32_t* bar, uint32_t target) {
  asm volatile("s_waitcnt vmcnt(0)" ::: "memory");  // my published stores are LLC-visible
  __syncthreads();
  if (threadIdx.x == 0) {
    uint32_t* leaf = bar + (blockIdx.x & 7) * 16;
    uint32_t* root = bar + 128;
    uint32_t* gen = bar + 144;
    const uint32_t leafsz = ((blockIdx.x & 7) < 2) ? 32u : 31u;  // 250 = 2*32 + 6*31
    uint32_t lo = __hip_atomic_fetch_add(leaf, 1u, __ATOMIC_RELAXED, __HIP_MEMORY_SCOPE_AGENT);
    if (lo == leafsz - 1) {
      __hip_atomic_store(leaf, 0u, __ATOMIC_RELAXED, __HIP_MEMORY_SCOPE_AGENT);
      uint32_t ro = __hip_atomic_fetch_add(root, 1u, __ATOMIC_RELAXED, __HIP_MEMORY_SCOPE_AGENT);
      if (ro == 7u) {
        __hip_atomic_store(root, 0u, __ATOMIC_RELAXED, __HIP_MEMORY_SCOPE_AGENT);
        __hip_atomic_store(gen, target, __ATOMIC_RELAXED, __HIP_MEMORY_SCOPE_AGENT);
      }
    }
    while (__hip_atomic_load(gen, __ATOMIC_RELAXED, __HIP_MEMORY_SCOPE_AGENT) < target)
      __builtin_amdgcn_s_sleep(1);
  }
  __syncthreads();
  asm volatile("" ::: "memory");  // compiler fence: no hoisting of gathers above the barrier
}

// CSR gather with agent-scope (LLC, stale-L2-proof) message loads.
__device__ __forceinline__ void gather_sc(const uint32_t* __restrict__ ed, int p0, int p1,
                                          uint32_t* buf, int lane, float& o0, float& o1) {
  float a0[PAD], a1[PAD];
#pragma unroll
  for (int j = 0; j < PAD; ++j) { a0[j] = 0.f; a1[j] = 0.f; }
#pragma unroll 2
  for (int p = p0; p < p1; p += PAD) {
    uint4 ea = *(const uint4*)(ed + p);
    uint4 eb = *(const uint4*)(ed + p + 4);
    uint32_t e[PAD] = {ea.x, ea.y, ea.z, ea.w, eb.x, eb.y, eb.z, eb.w};
    uint32_t v[PAD];
#pragma unroll
    for (int j = 0; j < PAD; ++j)
      v[j] = __hip_atomic_load(&buf[((e[j] & 0xFFFFu) << 6) + lane], __ATOMIC_RELAXED,
                               __HIP_MEMORY_SCOPE_AGENT);
#pragma unroll
    for (int j = 0; j < PAD; ++j) {
      float wj = __uint_as_float(e[j] & 0xFFFF0000u);
      a0[j] = fmaf(wj, bf2f_lo(v[j]), a0[j]);
      a1[j] = fmaf(wj, bf2f_hi(v[j]), a1[j]);
    }
  }
  o0 = ((a0[0] + a0[1]) + (a0[2] + a0[3])) + ((a0[4] + a0[5]) + (a0[6] + a0[7]));
  o1 = ((a1[0] + a1[1]) + (a1[2] + a1[3])) + ((a1[4] + a1[5]) + (a1[6] + a1[7]));
}

__global__ __launch_bounds__(MAIN_T, 2) void pc_main(
    const float* __restrict__ x, float* __restrict__ out,
    const int* __restrict__ offS, const uint32_t* __restrict__ edS,
    const int* __restrict__ offT, const uint32_t* __restrict__ edT,
    uint32_t* fx32, uint32_t* err32, const float* __restrict__ mask,
    uint32_t* bar, int N) {
  const int wid = threadIdx.x >> 6;
  const int lane = threadIdx.x & 63;
  const int n = blockIdx.x * (MAIN_T / 64) + wid;  // 0..1999, always valid (250*8 = 2000)
  const int i = (n << 6) + lane;
  const float m = mask[n];
  const int s0 = offS[n], s1 = offS[n + 1];
  const int t0 = offT[n], t1 = offT[n + 1];
  // transpose-in from registers: lane l owns batch (2l, 2l+1) of node n
  float x0 = x[(2 * lane) * N + n];
  float x1 = x[(2 * lane + 1) * N + n];
  float fx0 = tanhf(x0), fx1 = tanhf(x1);
  __hip_atomic_store(&fx32[i], pack_bf16x2(fx0, fx1), __ATOMIC_RELAXED, __HIP_MEMORY_SCOPE_AGENT);
  uint32_t gen = 0;
  gbar(bar, ++gen);

  for (int it = 0; it < NITER; ++it) {
    float mu0, mu1;
    gather_sc(edS, s0, s1, fx32, lane, mu0, mu1);
    const float e0 = (x0 - mu0) * m;
    const float e1 = (x1 - mu1) * m;
    __hip_atomic_store(&err32[i], pack_bf16x2(e0, e1), __ATOMIC_RELAXED, __HIP_MEMORY_SCOPE_AGENT);
    gbar(bar, ++gen);

    float a0, a1;
    gather_sc(edT, t0, t1, err32, lane, a0, a1);
    const float dx0 = e0 - (1.f - fx0 * fx0) * a0;
    const float dx1 = e1 - (1.f - fx1 * fx1) * a1;
    x0 -= 0.5f * dx0 * m;
    x1 -= 0.5f * dx1 * m;
    fx0 = tanhf(x0);
    fx1 = tanhf(x1);
    if (it < NITER - 1) {
      __hip_atomic_store(&fx32[i], pack_bf16x2(fx0, fx1), __ATOMIC_RELAXED,
                         __HIP_MEMORY_SCOPE_AGENT);
      gbar(bar, ++gen);
    }
  }
  // transpose-out from registers
  out[(2 * lane) * N + n] = x0;
  out[(2 * lane + 1) * N + n] = x1;
}

// ---------------- host ----------------

extern "C" void kernel_launch(void* const* d_in, const int* in_sizes, int n_in,
                              void* d_out, int out_size, void* d_ws, size_t ws_size,
                              hipStream_t stream) {
  const float* x = (const float*)d_in[0];
  const int* ei = (const int*)d_in[1];
  const float* w = (const float*)d_in[2];
  const float* mask = (const float*)d_in[3];
  const int E = in_sizes[2];  // 131072
  int N = in_sizes[3];        // 2000
  const int* src = ei;
  const int* tgt = ei + E;
  float* out = (float*)d_out;

  const int Epad = E + PAD * N;  // per-node pad-to-PAD headroom

  size_t off = 0;
  auto alloc = [&](size_t bytes) -> void* {
    off = (off + 255) & ~(size_t)255;
    void* p = (char*)d_ws + off;
    off += bytes;
    return p;
  };
  uint32_t* edgeS = (uint32_t*)alloc((size_t)Epad * 4);  // contiguous with edgeT for one zero pass
  uint32_t* edgeT = (uint32_t*)alloc((size_t)Epad * 4);
  int* partS = (int*)alloc(8 * 2048 * 4);
  int* partT = (int*)alloc(8 * 2048 * 4);
  int* offS = (int*)alloc(2048 * 4);
  int* offT = (int*)alloc(2048 * 4);
  int* curS = (int*)alloc(2048 * 4);
  int* curT = (int*)alloc(2048 * 4);
  uint32_t* fx32 = (uint32_t*)alloc((size_t)N * 64 * 4);
  uint32_t* err32 = (uint32_t*)alloc((size_t)N * 64 * 4);
  uint32_t* bar = (uint32_t*)alloc(256 * 4);

  hist_zero_kernel<<<32, 1024, 0, stream>>>(src, tgt, partS, partT, edgeS, E, N, 2 * Epad);
  scan_pad_kernel<<<2, 256, 0, stream>>>(partS, partT, offS, offT, curS, curT, bar, N);
  scatter_kernel<<<(E + 255) / 256, 256, 0, stream>>>(src, tgt, w, curS, curT, edgeS, edgeT, E);

  void* args[] = {(void*)&x,    (void*)&out,   (void*)&offS, (void*)&edgeS,
                  (void*)&offT, (void*)&edgeT, (void*)&fx32, (void*)&err32,
                  (void*)&mask, (void*)&bar,   (void*)&N};
  hipLaunchCooperativeKernel((const void*)pc_main, dim3(NBLK), dim3(MAIN_T), args, 0, stream);
}